// Round 1
// baseline (4097.150 us; speedup 1.0000x reference)
//
#include <hip/hip_runtime.h>
#include <stdint.h>

// SymmetricContraction (MACE) on MI355X — symmetrized-monomial rewrite.
//
// out[b,c,m] = sum_{i,j,l} x_i x_j x_l * C3[m,j,l,i]  (C3 = U3 . w3(e,c))
//            + sum_{j,l}   x_j x_l     * C2[m,j,l]
//            + sum_{j}     x_j         * C1[m,j]
// The monomials are permutation-symmetric -> collapse the 16^3 cube to
// 816 sorted triples (+136 pairs +16 singles) with permutation-summed
// coefficients. Both output irreps (M0=1, M1=3) are fused: each monomial's
// 4 coefficient slots are one float4 -> one ds_read_b128 feeds 4 outputs
// and (with 2 nodes/thread) 8 FMAs/slot. This cuts the LDS broadcast
// traffic ~8.6x vs the previous version (which was LDS-pipe bound).
//
// prep_kernel (once per launch): symmetrize U3/U2 into ws (perm-sum with
// stabilizer division), build per-element node lists.
// sc_main: grid (c,e); build fused per-(c,e) table in LDS (13KB+2KB),
// then fully-unrolled triangular polynomial, 2 nodes per thread.

#define BN 2048
#define CN 128
#define EN 10

#define NT3 816   // #sorted triples a<=b<=c in [0,16)
#define NT2 136   // #sorted pairs a<=b
#define K3_0 23
#define K3_1 33
#define K2_0 4
#define K2_1 5

// ws layout (float offsets)
#define U3S0_OFF 0                          // [23][816]
#define U3S1_OFF (K3_0*NT3)                 // 18768: [3][33][816]
#define U2S0_OFF (U3S1_OFF + 3*K3_1*NT3)    // 99552: [4][136]
#define U2S1_OFF (U2S0_OFF + K2_0*NT2)      // 100096: [3][5][136]
#define LISTS_OFF (U2S1_OFF + 3*K2_1*NT2)   // 102136: int[10][2048]
#define CNT_OFF (LISTS_OFF + EN*BN)         // 122616: int[10]
// total ~490 KB of workspace

__global__ __launch_bounds__(256) void prep_kernel(
    const float* __restrict__ U3_0, const float* __restrict__ U2_0,
    const float* __restrict__ U3_1, const float* __restrict__ U2_1,
    const float* __restrict__ yg, float* __restrict__ ws)
{
    const int bid = blockIdx.x, tid = threadIdx.x;
    if (bid < 16) {
        const int N0 = K3_0*NT3, N1 = 3*K3_1*NT3, P0 = K2_0*NT2, P1 = 3*K2_1*NT2;
        const int TOT = N0 + N1 + P0 + P1;
        for (int it = bid*256 + tid; it < TOT; it += 16*256) {
            if (it < N0 + N1) {
                // ---- symmetrize a triple coefficient ----
                const float* U3; int m, k, K, t, dst;
                if (it < N0) { U3 = U3_0; K = K3_0; m = 0; k = it / NT3; t = it - k*NT3; dst = U3S0_OFF + it; }
                else { int r = it - N0; U3 = U3_1; K = K3_1; int mk = r / NT3; t = r - mk*NT3;
                       m = mk / K3_1; k = mk - m*K3_1; dst = U3S1_OFF + r; }
                // unrank t -> (a<=b<=cc), lexicographic (matches main's loop order)
                int a = 0, rem = t;
                while (rem >= ((16-a)*(17-a))/2) { rem -= ((16-a)*(17-a))/2; ++a; }
                int b = a;
                while (rem >= 16-b) { rem -= 16-b; ++b; }
                const int cc = b + rem;
                // sum U3[m,i,j,l,k]*... over all 6 orderings, divide by stabilizer
                #define AT3(i,j,l) U3[(size_t)(((m*16+(i))*16+(j))*16+(l))*K + k]
                float D = AT3(a,b,cc) + AT3(a,cc,b) + AT3(b,a,cc)
                        + AT3(b,cc,a) + AT3(cc,a,b) + AT3(cc,b,a);
                #undef AT3
                const int eq = (a==b) + (b==cc);
                D *= (eq==2) ? (1.f/6.f) : (eq==1) ? 0.5f : 1.f;
                ws[dst] = D;
            } else {
                // ---- symmetrize a pair coefficient ----
                const int it2 = it - (N0+N1);
                const float* U2; int m, k, K, pr, dst;
                if (it2 < P0) { U2 = U2_0; K = K2_0; m = 0; k = it2 / NT2; pr = it2 - k*NT2; dst = U2S0_OFF + it2; }
                else { int r = it2 - P0; U2 = U2_1; K = K2_1; int mk = r / NT2; pr = r - mk*NT2;
                       m = mk / K2_1; k = mk - m*K2_1; dst = U2S1_OFF + r; }
                int a = 0, rem = pr;
                while (rem >= 16-a) { rem -= 16-a; ++a; }
                const int b = a + rem;
                float D = U2[(size_t)((m*16+a)*16+b)*K + k]
                        + U2[(size_t)((m*16+b)*16+a)*K + k];
                if (a == b) D *= 0.5f;
                ws[dst] = D;
            }
        }
    } else if (bid < 16 + EN) {
        // ---- per-element node list (y is exactly one-hot) ----
        const int e = bid - 16;
        __shared__ int lcnt;
        if (tid == 0) lcnt = 0;
        __syncthreads();
        int* lists = (int*)(ws + LISTS_OFF);
        for (int b = tid; b < BN; b += 256) {
            if (yg[b*EN + e] > 0.5f) {
                int p = atomicAdd(&lcnt, 1);
                lists[e*BN + p] = b;
            }
        }
        __syncthreads();
        if (tid == 0) ((int*)(ws + CNT_OFF))[e] = lcnt;
    }
}

__global__ __launch_bounds__(128, 2) void sc_main(
    const float* __restrict__ xg,
    const float* __restrict__ U1_0, const float* __restrict__ U1_1,
    const float* __restrict__ W3_0, const float* __restrict__ W2_0, const float* __restrict__ W1_0,
    const float* __restrict__ W3_1, const float* __restrict__ W2_1, const float* __restrict__ W1_1,
    const float* __restrict__ ws, float* __restrict__ outg)
{
    const int c = blockIdx.x, e = blockIdx.y, tid = threadIdx.x;
    __shared__ float4 T3s[NT3];   // [triple] -> 4 fused output slots
    __shared__ float4 T2s[NT2];
    __shared__ float4 T1s[16];

    // per-(e,c) weight vectors, uniform across block, in registers (build only)
    float wk30[K3_0], wk31[K3_1], wk20[K2_0], wk21[K2_1];
#pragma unroll
    for (int k = 0; k < K3_0; ++k) wk30[k] = W3_0[(e*K3_0 + k)*CN + c];
#pragma unroll
    for (int k = 0; k < K3_1; ++k) wk31[k] = W3_1[(e*K3_1 + k)*CN + c];
#pragma unroll
    for (int k = 0; k < K2_0; ++k) wk20[k] = W2_0[(e*K2_0 + k)*CN + c];
#pragma unroll
    for (int k = 0; k < K2_1; ++k) wk21[k] = W2_1[(e*K2_1 + k)*CN + c];
    const float wk10 = W1_0[e*CN + c];
    const float wk11 = W1_1[e*CN + c];

    // ---- build T3: contract symmetrized U3 with wk, 4 triples per thread-iter
    const float* u3s0 = ws + U3S0_OFF;
    const float* u3s1 = ws + U3S1_OFF;
    for (int g = tid; g < NT3/4; g += 128) {
        float4 A0 = make_float4(0,0,0,0), A1 = A0, A2 = A0, A3 = A0;
#pragma unroll
        for (int k = 0; k < K3_0; ++k) {
            const float w = wk30[k];
            const float4 u = ((const float4*)(u3s0 + k*NT3))[g];
            A0.x = fmaf(u.x, w, A0.x); A0.y = fmaf(u.y, w, A0.y);
            A0.z = fmaf(u.z, w, A0.z); A0.w = fmaf(u.w, w, A0.w);
        }
#pragma unroll
        for (int k = 0; k < K3_1; ++k) {
            const float w = wk31[k];
            const float4 ua = ((const float4*)(u3s1 + k*NT3))[g];
            A1.x = fmaf(ua.x, w, A1.x); A1.y = fmaf(ua.y, w, A1.y);
            A1.z = fmaf(ua.z, w, A1.z); A1.w = fmaf(ua.w, w, A1.w);
            const float4 ub = ((const float4*)(u3s1 + (K3_1 + k)*NT3))[g];
            A2.x = fmaf(ub.x, w, A2.x); A2.y = fmaf(ub.y, w, A2.y);
            A2.z = fmaf(ub.z, w, A2.z); A2.w = fmaf(ub.w, w, A2.w);
            const float4 uc = ((const float4*)(u3s1 + (2*K3_1 + k)*NT3))[g];
            A3.x = fmaf(uc.x, w, A3.x); A3.y = fmaf(uc.y, w, A3.y);
            A3.z = fmaf(uc.z, w, A3.z); A3.w = fmaf(uc.w, w, A3.w);
        }
        T3s[4*g+0] = make_float4(A0.x, A1.x, A2.x, A3.x);
        T3s[4*g+1] = make_float4(A0.y, A1.y, A2.y, A3.y);
        T3s[4*g+2] = make_float4(A0.z, A1.z, A2.z, A3.z);
        T3s[4*g+3] = make_float4(A0.w, A1.w, A2.w, A3.w);
    }
    // ---- build T2
    const float* u2s0 = ws + U2S0_OFF;
    const float* u2s1 = ws + U2S1_OFF;
    for (int g = tid; g < NT2/4; g += 128) {
        float4 A0 = make_float4(0,0,0,0), A1 = A0, A2 = A0, A3 = A0;
#pragma unroll
        for (int k = 0; k < K2_0; ++k) {
            const float w = wk20[k];
            const float4 u = ((const float4*)(u2s0 + k*NT2))[g];
            A0.x = fmaf(u.x, w, A0.x); A0.y = fmaf(u.y, w, A0.y);
            A0.z = fmaf(u.z, w, A0.z); A0.w = fmaf(u.w, w, A0.w);
        }
#pragma unroll
        for (int k = 0; k < K2_1; ++k) {
            const float w = wk21[k];
            const float4 ua = ((const float4*)(u2s1 + k*NT2))[g];
            A1.x = fmaf(ua.x, w, A1.x); A1.y = fmaf(ua.y, w, A1.y);
            A1.z = fmaf(ua.z, w, A1.z); A1.w = fmaf(ua.w, w, A1.w);
            const float4 ub = ((const float4*)(u2s1 + (K2_1 + k)*NT2))[g];
            A2.x = fmaf(ub.x, w, A2.x); A2.y = fmaf(ub.y, w, A2.y);
            A2.z = fmaf(ub.z, w, A2.z); A2.w = fmaf(ub.w, w, A2.w);
            const float4 uc = ((const float4*)(u2s1 + (2*K2_1 + k)*NT2))[g];
            A3.x = fmaf(uc.x, w, A3.x); A3.y = fmaf(uc.y, w, A3.y);
            A3.z = fmaf(uc.z, w, A3.z); A3.w = fmaf(uc.w, w, A3.w);
        }
        T2s[4*g+0] = make_float4(A0.x, A1.x, A2.x, A3.x);
        T2s[4*g+1] = make_float4(A0.y, A1.y, A2.y, A3.y);
        T2s[4*g+2] = make_float4(A0.z, A1.z, A2.z, A3.z);
        T2s[4*g+3] = make_float4(A0.w, A1.w, A2.w, A3.w);
    }
    // ---- build T1 (K1 == 1); U1 layout [M][16][1]
    if (tid < 16) {
        const int j = tid;
        T1s[j] = make_float4(U1_0[j]*wk10, U1_1[j]*wk11,
                             U1_1[16+j]*wk11, U1_1[32+j]*wk11);
    }

    const int* lists = (const int*)(ws + LISTS_OFF) + e*BN;
    const int cnt = ((const int*)(ws + CNT_OFF))[e];
    __syncthreads();

    // ---- node loop: 2 nodes per thread, coefficient reads amortized
    for (int base = 0; base < cnt; base += 256) {
        const int s0 = base + tid, s1 = base + tid + 128;
        const bool act0 = s0 < cnt, act1 = s1 < cnt;
        const int n0 = lists[act0 ? s0 : 0];
        const int n1 = lists[act1 ? s1 : 0];
        const float4* p0 = (const float4*)(xg + ((size_t)n0*CN + c)*16);
        const float4* p1 = (const float4*)(xg + ((size_t)n1*CN + c)*16);
        float x0[16], x1[16];
#pragma unroll
        for (int d = 0; d < 4; ++d) {
            const float4 v0 = p0[d]; const float4 v1 = p1[d];
            x0[4*d+0]=v0.x; x0[4*d+1]=v0.y; x0[4*d+2]=v0.z; x0[4*d+3]=v0.w;
            x1[4*d+0]=v1.x; x1[4*d+1]=v1.y; x1[4*d+2]=v1.z; x1[4*d+3]=v1.w;
        }
        float acc00=0.f, acc01=0.f, acc02=0.f, acc03=0.f;
        float acc10=0.f, acc11=0.f, acc12=0.f, acc13=0.f;
        int t = 0, pr = 0;
#pragma unroll
        for (int a = 0; a < 16; ++a) {
#pragma unroll
            for (int b = a; b < 16; ++b) {
                const float pA = x0[a]*x0[b];
                const float pB = x1[a]*x1[b];
                const float4 c2 = T2s[pr];
                acc00 = fmaf(c2.x, pA, acc00); acc01 = fmaf(c2.y, pA, acc01);
                acc02 = fmaf(c2.z, pA, acc02); acc03 = fmaf(c2.w, pA, acc03);
                acc10 = fmaf(c2.x, pB, acc10); acc11 = fmaf(c2.y, pB, acc11);
                acc12 = fmaf(c2.z, pB, acc12); acc13 = fmaf(c2.w, pB, acc13);
#pragma unroll
                for (int cc = b; cc < 16; ++cc) {
                    const float qA = pA*x0[cc];
                    const float qB = pB*x1[cc];
                    const float4 c3 = T3s[t];
                    acc00 = fmaf(c3.x, qA, acc00); acc01 = fmaf(c3.y, qA, acc01);
                    acc02 = fmaf(c3.z, qA, acc02); acc03 = fmaf(c3.w, qA, acc03);
                    acc10 = fmaf(c3.x, qB, acc10); acc11 = fmaf(c3.y, qB, acc11);
                    acc12 = fmaf(c3.z, qB, acc12); acc13 = fmaf(c3.w, qB, acc13);
                    ++t;
                }
                ++pr;
            }
            const float4 c1 = T1s[a];
            acc00 = fmaf(c1.x, x0[a], acc00); acc01 = fmaf(c1.y, x0[a], acc01);
            acc02 = fmaf(c1.z, x0[a], acc02); acc03 = fmaf(c1.w, x0[a], acc03);
            acc10 = fmaf(c1.x, x1[a], acc10); acc11 = fmaf(c1.y, x1[a], acc11);
            acc12 = fmaf(c1.z, x1[a], acc12); acc13 = fmaf(c1.w, x1[a], acc13);
        }
        if (act0) {
            float* o = outg + (size_t)n0*512;
            o[c] = acc00;
            o[128 + c*3 + 0] = acc01; o[128 + c*3 + 1] = acc02; o[128 + c*3 + 2] = acc03;
        }
        if (act1) {
            float* o = outg + (size_t)n1*512;
            o[c] = acc10;
            o[128 + c*3 + 0] = acc11; o[128 + c*3 + 1] = acc12; o[128 + c*3 + 2] = acc13;
        }
    }
}

extern "C" void kernel_launch(void* const* d_in, const int* in_sizes, int n_in,
                              void* d_out, int out_size, void* d_ws, size_t ws_size,
                              hipStream_t stream) {
    const float* x = (const float*)d_in[0];
    const float* y = (const float*)d_in[1];
    const float* U3_0 = (const float*)d_in[2];
    const float* U2_0 = (const float*)d_in[3];
    const float* U1_0 = (const float*)d_in[4];
    const float* W3_0 = (const float*)d_in[5];
    const float* W2_0 = (const float*)d_in[6];
    const float* W1_0 = (const float*)d_in[7];
    const float* U3_1 = (const float*)d_in[8];
    const float* U2_1 = (const float*)d_in[9];
    const float* U1_1 = (const float*)d_in[10];
    const float* W3_1 = (const float*)d_in[11];
    const float* W2_1 = (const float*)d_in[12];
    const float* W1_1 = (const float*)d_in[13];
    float* out = (float*)d_out;
    float* ws = (float*)d_ws;  // needs ~490 KB

    prep_kernel<<<dim3(16 + EN), 256, 0, stream>>>(U3_0, U2_0, U3_1, U2_1, y, ws);
    dim3 grid(CN, EN);
    sc_main<<<grid, 128, 0, stream>>>(x, U1_0, U1_1,
                                      W3_0, W2_0, W1_0,
                                      W3_1, W2_1, W1_1, ws, out);
}

// Round 2
// 319.467 us; speedup vs baseline: 12.8250x; 12.8250x over previous
//
#include <hip/hip_runtime.h>
#include <stdint.h>

// SymmetricContraction (MACE) on MI355X — symmetrized monomials, scratch-free.
//
// out[b,c,m] = sum_{a<=b<=cc} x_a x_b x_cc * T3[t(a,b,cc)]   (perm-summed U3.w3)
//            + sum_{a<=b}     x_a x_b      * T2[pr(a,b)]
//            + sum_{a}        x_a          * T1[a]
// Both output irreps fused: each monomial's 4 output slots are one float4 in
// LDS -> one ds_read_b128 broadcast feeds 4 outputs x 2 nodes = 8 FMAs.
// Round-1 failure: full unroll was refused -> x0[]/x1[] runtime-indexed ->
// scratch (3+3.6 GB TCC traffic, VALUBusy 1.4%). Fix: x lives in LDS columns
// (xs[i][tid], bank-conflict-free, thread-private so no barriers); inner
// loops stay runtime with small bodies; registers hold scalars only.

#define BN 2048
#define CN 128
#define EN 10

#define NT3 816   // #sorted triples a<=b<=cc in [0,16)
#define NT2 136   // #sorted pairs a<=b
#define K3_0 23
#define K3_1 33
#define K2_0 4
#define K2_1 5

// ws layout (float offsets)
#define U3S0_OFF 0                          // [23][816]
#define U3S1_OFF (K3_0*NT3)                 // [3][33][816]
#define U2S0_OFF (U3S1_OFF + 3*K3_1*NT3)    // [4][136]
#define U2S1_OFF (U2S0_OFF + K2_0*NT2)      // [3][5][136]
#define LISTS_OFF (U2S1_OFF + 3*K2_1*NT2)   // int[10][2048]
#define CNT_OFF (LISTS_OFF + EN*BN)         // int[10]

__global__ __launch_bounds__(256) void prep_kernel(
    const float* __restrict__ U3_0, const float* __restrict__ U2_0,
    const float* __restrict__ U3_1, const float* __restrict__ U2_1,
    const float* __restrict__ yg, float* __restrict__ ws)
{
    const int bid = blockIdx.x, tid = threadIdx.x;
    if (bid < 32) {
        const int N0 = K3_0*NT3, N1 = 3*K3_1*NT3, P0 = K2_0*NT2, P1 = 3*K2_1*NT2;
        const int TOT = N0 + N1 + P0 + P1;
        for (int it = bid*256 + tid; it < TOT; it += 32*256) {
            if (it < N0 + N1) {
                const float* U3; int m, k, K, t, dst;
                if (it < N0) { U3 = U3_0; K = K3_0; m = 0; k = it / NT3; t = it - k*NT3; dst = U3S0_OFF + it; }
                else { int r = it - N0; U3 = U3_1; K = K3_1; int mk = r / NT3; t = r - mk*NT3;
                       m = mk / K3_1; k = mk - m*K3_1; dst = U3S1_OFF + r; }
                // unrank t -> (a<=b<=cc), lexicographic (matches main's loop order)
                int a = 0, rem = t;
                while (rem >= ((16-a)*(17-a))/2) { rem -= ((16-a)*(17-a))/2; ++a; }
                int b = a;
                while (rem >= 16-b) { rem -= 16-b; ++b; }
                const int cc = b + rem;
                #define AT3(i,j,l) U3[(size_t)(((m*16+(i))*16+(j))*16+(l))*K + k]
                float D = AT3(a,b,cc) + AT3(a,cc,b) + AT3(b,a,cc)
                        + AT3(b,cc,a) + AT3(cc,a,b) + AT3(cc,b,a);
                #undef AT3
                const int eq = (a==b) + (b==cc);
                D *= (eq==2) ? (1.f/6.f) : (eq==1) ? 0.5f : 1.f;
                ws[dst] = D;
            } else {
                const int it2 = it - (N0+N1);
                const float* U2; int m, k, K, pr, dst;
                if (it2 < P0) { U2 = U2_0; K = K2_0; m = 0; k = it2 / NT2; pr = it2 - k*NT2; dst = U2S0_OFF + it2; }
                else { int r = it2 - P0; U2 = U2_1; K = K2_1; int mk = r / NT2; pr = r - mk*NT2;
                       m = mk / K2_1; k = mk - m*K2_1; dst = U2S1_OFF + r; }
                int a = 0, rem = pr;
                while (rem >= 16-a) { rem -= 16-a; ++a; }
                const int b = a + rem;
                float D = U2[(size_t)((m*16+a)*16+b)*K + k]
                        + U2[(size_t)((m*16+b)*16+a)*K + k];
                if (a == b) D *= 0.5f;
                ws[dst] = D;
            }
        }
    } else if (bid < 32 + EN) {
        const int e = bid - 32;
        __shared__ int lcnt;
        if (tid == 0) lcnt = 0;
        __syncthreads();
        int* lists = (int*)(ws + LISTS_OFF);
        for (int b = tid; b < BN; b += 256) {
            if (yg[b*EN + e] > 0.5f) {
                int p = atomicAdd(&lcnt, 1);
                lists[e*BN + p] = b;
            }
        }
        __syncthreads();
        if (tid == 0) ((int*)(ws + CNT_OFF))[e] = lcnt;
    }
}

__global__ __launch_bounds__(128) void sc_main(
    const float* __restrict__ xg,
    const float* __restrict__ U1_0, const float* __restrict__ U1_1,
    const float* __restrict__ W3_0, const float* __restrict__ W2_0, const float* __restrict__ W1_0,
    const float* __restrict__ W3_1, const float* __restrict__ W2_1, const float* __restrict__ W1_1,
    const float* __restrict__ ws, float* __restrict__ outg)
{
    const int c = blockIdx.x, e = blockIdx.y, tid = threadIdx.x;
    __shared__ float4 T3s[NT3];        // 13056 B
    __shared__ float4 T2s[NT2];        //  2176 B
    __shared__ float4 T1s[16];         //   256 B
    __shared__ float xs0[16*128];      //  8192 B  (x[i] of node slot0, column tid)
    __shared__ float xs1[16*128];      //  8192 B
    __shared__ float wk30s[K3_0], wk31s[K3_1], wk20s[K2_0], wk21s[K2_1];

    // per-(e,c) weights into LDS (block-uniform; avoids register arrays)
    if (tid < K3_0) wk30s[tid] = W3_0[(e*K3_0 + tid)*CN + c];
    if (tid >= 32 && tid < 32 + K3_1) wk31s[tid-32] = W3_1[(e*K3_1 + (tid-32))*CN + c];
    if (tid >= 72 && tid < 72 + K2_0) wk20s[tid-72] = W2_0[(e*K2_0 + (tid-72))*CN + c];
    if (tid >= 80 && tid < 80 + K2_1) wk21s[tid-80] = W2_1[(e*K2_1 + (tid-80))*CN + c];
    __syncthreads();

    // ---- build T3 (4 triples per iter); coefficients read as float4 rows
    const float* u3s0 = ws + U3S0_OFF;
    const float* u3s1 = ws + U3S1_OFF;
    for (int g = tid; g < NT3/4; g += 128) {
        float4 A0 = make_float4(0,0,0,0), A1 = A0, A2 = A0, A3 = A0;
#pragma unroll
        for (int k = 0; k < K3_0; ++k) {
            const float w = wk30s[k];
            const float4 u = ((const float4*)(u3s0 + k*NT3))[g];
            A0.x = fmaf(u.x, w, A0.x); A0.y = fmaf(u.y, w, A0.y);
            A0.z = fmaf(u.z, w, A0.z); A0.w = fmaf(u.w, w, A0.w);
        }
#pragma unroll
        for (int k = 0; k < K3_1; ++k) {
            const float w = wk31s[k];
            const float4 ua = ((const float4*)(u3s1 + k*NT3))[g];
            A1.x = fmaf(ua.x, w, A1.x); A1.y = fmaf(ua.y, w, A1.y);
            A1.z = fmaf(ua.z, w, A1.z); A1.w = fmaf(ua.w, w, A1.w);
            const float4 ub = ((const float4*)(u3s1 + (K3_1 + k)*NT3))[g];
            A2.x = fmaf(ub.x, w, A2.x); A2.y = fmaf(ub.y, w, A2.y);
            A2.z = fmaf(ub.z, w, A2.z); A2.w = fmaf(ub.w, w, A2.w);
            const float4 uc = ((const float4*)(u3s1 + (2*K3_1 + k)*NT3))[g];
            A3.x = fmaf(uc.x, w, A3.x); A3.y = fmaf(uc.y, w, A3.y);
            A3.z = fmaf(uc.z, w, A3.z); A3.w = fmaf(uc.w, w, A3.w);
        }
        T3s[4*g+0] = make_float4(A0.x, A1.x, A2.x, A3.x);
        T3s[4*g+1] = make_float4(A0.y, A1.y, A2.y, A3.y);
        T3s[4*g+2] = make_float4(A0.z, A1.z, A2.z, A3.z);
        T3s[4*g+3] = make_float4(A0.w, A1.w, A2.w, A3.w);
    }
    // ---- build T2
    const float* u2s0 = ws + U2S0_OFF;
    const float* u2s1 = ws + U2S1_OFF;
    for (int g = tid; g < NT2/4; g += 128) {
        float4 A0 = make_float4(0,0,0,0), A1 = A0, A2 = A0, A3 = A0;
#pragma unroll
        for (int k = 0; k < K2_0; ++k) {
            const float w = wk20s[k];
            const float4 u = ((const float4*)(u2s0 + k*NT2))[g];
            A0.x = fmaf(u.x, w, A0.x); A0.y = fmaf(u.y, w, A0.y);
            A0.z = fmaf(u.z, w, A0.z); A0.w = fmaf(u.w, w, A0.w);
        }
#pragma unroll
        for (int k = 0; k < K2_1; ++k) {
            const float w = wk21s[k];
            const float4 ua = ((const float4*)(u2s1 + k*NT2))[g];
            A1.x = fmaf(ua.x, w, A1.x); A1.y = fmaf(ua.y, w, A1.y);
            A1.z = fmaf(ua.z, w, A1.z); A1.w = fmaf(ua.w, w, A1.w);
            const float4 ub = ((const float4*)(u2s1 + (K2_1 + k)*NT2))[g];
            A2.x = fmaf(ub.x, w, A2.x); A2.y = fmaf(ub.y, w, A2.y);
            A2.z = fmaf(ub.z, w, A2.z); A2.w = fmaf(ub.w, w, A2.w);
            const float4 uc = ((const float4*)(u2s1 + (2*K2_1 + k)*NT2))[g];
            A3.x = fmaf(uc.x, w, A3.x); A3.y = fmaf(uc.y, w, A3.y);
            A3.z = fmaf(uc.z, w, A3.z); A3.w = fmaf(uc.w, w, A3.w);
        }
        T2s[4*g+0] = make_float4(A0.x, A1.x, A2.x, A3.x);
        T2s[4*g+1] = make_float4(A0.y, A1.y, A2.y, A3.y);
        T2s[4*g+2] = make_float4(A0.z, A1.z, A2.z, A3.z);
        T2s[4*g+3] = make_float4(A0.w, A1.w, A2.w, A3.w);
    }
    // ---- build T1 (K1 == 1); U1 layout [M][16][1]
    if (tid < 16) {
        const float wk10 = W1_0[e*CN + c];
        const float wk11 = W1_1[e*CN + c];
        const int j = tid;
        T1s[j] = make_float4(U1_0[j]*wk10, U1_1[j]*wk11,
                             U1_1[16+j]*wk11, U1_1[32+j]*wk11);
    }

    const int* lists = (const int*)(ws + LISTS_OFF) + e*BN;
    const int cnt = ((const int*)(ws + CNT_OFF))[e];
    __syncthreads();

    // ---- node loop: 2 nodes/thread; x in LDS columns (thread-private,
    // conflict-free, no barriers); registers hold scalars only.
    for (int base = 0; base < cnt; base += 256) {
        const int s0 = base + tid, s1 = base + tid + 128;
        const bool act0 = s0 < cnt, act1 = s1 < cnt;
        const int n0 = lists[act0 ? s0 : 0];
        const int n1 = lists[act1 ? s1 : 0];
        const float4* p0 = (const float4*)(xg + ((size_t)n0*CN + c)*16);
        const float4* p1 = (const float4*)(xg + ((size_t)n1*CN + c)*16);
#pragma unroll
        for (int d = 0; d < 4; ++d) {
            const float4 v0 = p0[d]; const float4 v1 = p1[d];
            xs0[(4*d+0)*128+tid] = v0.x; xs0[(4*d+1)*128+tid] = v0.y;
            xs0[(4*d+2)*128+tid] = v0.z; xs0[(4*d+3)*128+tid] = v0.w;
            xs1[(4*d+0)*128+tid] = v1.x; xs1[(4*d+1)*128+tid] = v1.y;
            xs1[(4*d+2)*128+tid] = v1.z; xs1[(4*d+3)*128+tid] = v1.w;
        }

        float acc00=0.f, acc01=0.f, acc02=0.f, acc03=0.f;
        float acc10=0.f, acc11=0.f, acc12=0.f, acc13=0.f;
        int t = 0, pr = 0;
#pragma unroll 1
        for (int a = 0; a < 16; ++a) {
            const float xa0 = xs0[a*128+tid];
            const float xa1 = xs1[a*128+tid];
            const float4 c1 = T1s[a];
            acc00 = fmaf(c1.x, xa0, acc00); acc01 = fmaf(c1.y, xa0, acc01);
            acc02 = fmaf(c1.z, xa0, acc02); acc03 = fmaf(c1.w, xa0, acc03);
            acc10 = fmaf(c1.x, xa1, acc10); acc11 = fmaf(c1.y, xa1, acc11);
            acc12 = fmaf(c1.z, xa1, acc12); acc13 = fmaf(c1.w, xa1, acc13);
#pragma unroll 1
            for (int b = a; b < 16; ++b) {
                const float xb0 = xs0[b*128+tid];
                const float xb1 = xs1[b*128+tid];
                const float pA = xa0*xb0;
                const float pB = xa1*xb1;
                const float4 c2 = T2s[pr]; ++pr;
                acc00 = fmaf(c2.x, pA, acc00); acc01 = fmaf(c2.y, pA, acc01);
                acc02 = fmaf(c2.z, pA, acc02); acc03 = fmaf(c2.w, pA, acc03);
                acc10 = fmaf(c2.x, pB, acc10); acc11 = fmaf(c2.y, pB, acc11);
                acc12 = fmaf(c2.z, pB, acc12); acc13 = fmaf(c2.w, pB, acc13);
#pragma unroll 4
                for (int cc = b; cc < 16; ++cc) {
                    const float xc0 = xs0[cc*128+tid];
                    const float xc1 = xs1[cc*128+tid];
                    const float4 c3 = T3s[t]; ++t;
                    const float qA = pA*xc0;
                    const float qB = pB*xc1;
                    acc00 = fmaf(c3.x, qA, acc00); acc01 = fmaf(c3.y, qA, acc01);
                    acc02 = fmaf(c3.z, qA, acc02); acc03 = fmaf(c3.w, qA, acc03);
                    acc10 = fmaf(c3.x, qB, acc10); acc11 = fmaf(c3.y, qB, acc11);
                    acc12 = fmaf(c3.z, qB, acc12); acc13 = fmaf(c3.w, qB, acc13);
                }
            }
        }
        if (act0) {
            float* o = outg + (size_t)n0*512;
            o[c] = acc00;
            o[128 + c*3 + 0] = acc01; o[128 + c*3 + 1] = acc02; o[128 + c*3 + 2] = acc03;
        }
        if (act1) {
            float* o = outg + (size_t)n1*512;
            o[c] = acc10;
            o[128 + c*3 + 0] = acc11; o[128 + c*3 + 1] = acc12; o[128 + c*3 + 2] = acc13;
        }
    }
}

extern "C" void kernel_launch(void* const* d_in, const int* in_sizes, int n_in,
                              void* d_out, int out_size, void* d_ws, size_t ws_size,
                              hipStream_t stream) {
    const float* x = (const float*)d_in[0];
    const float* y = (const float*)d_in[1];
    const float* U3_0 = (const float*)d_in[2];
    const float* U2_0 = (const float*)d_in[3];
    const float* U1_0 = (const float*)d_in[4];
    const float* W3_0 = (const float*)d_in[5];
    const float* W2_0 = (const float*)d_in[6];
    const float* W1_0 = (const float*)d_in[7];
    const float* U3_1 = (const float*)d_in[8];
    const float* U2_1 = (const float*)d_in[9];
    const float* U1_1 = (const float*)d_in[10];
    const float* W3_1 = (const float*)d_in[11];
    const float* W2_1 = (const float*)d_in[12];
    const float* W1_1 = (const float*)d_in[13];
    float* out = (float*)d_out;
    float* ws = (float*)d_ws;  // ~490 KB

    prep_kernel<<<dim3(32 + EN), 256, 0, stream>>>(U3_0, U2_0, U3_1, U2_1, y, ws);
    dim3 grid(CN, EN);
    sc_main<<<grid, 128, 0, stream>>>(x, U1_0, U1_1,
                                      W3_0, W2_0, W1_0,
                                      W3_1, W2_1, W1_1, ws, out);
}

// Round 3
// 194.489 us; speedup vs baseline: 21.0662x; 1.6426x over previous
//
#include <hip/hip_runtime.h>
#include <stdint.h>

// SymmetricContraction (MACE) on MI355X — symmetrized monomials, 3-kernel split.
//
// out[b,c,m] = sum_{a<=b<=cc} x_a x_b x_cc * T3 + sum_{a<=b} x_a x_b * T2 + sum_a x_a * T1
// evaluated in full Horner form:
//   out = sum_a x_a * ( T1[a] + sum_{b>=a} x_b * ( T2[ab] + sum_{cc>=b} x_cc * T3[abcc] ) )
// Both output irreps fused into float4 slots (0e m=0 | 1o m=0..2).
//
// prep_sym  : symmetrize U3/U2 into ws (1 output/thread, 410 blocks) + node lists.
// sc_build  : per (c,e) contract symmetrized U with W -> fused table (968 float4)
//             written to ws (19.8 MB). Keeps the register-fat phase out of the
//             node kernel (round-2: VGPR=256 -> 9.8% occupancy).
// sc_apply  : node loop only. Table global->LDS, x in LDS columns, pure FMA.
// Fallback  : if ws too small, round-2 fused kernel (proven 223 us).

#define BN 2048
#define CN 128
#define EN 10

#define NT3 816   // #sorted triples a<=b<=cc in [0,16)
#define NT2 136   // #sorted pairs a<=b
#define NTT (NT3 + NT2 + 16)   // 968 fused table entries (float4 each)
#define K3_0 23
#define K3_1 33
#define K2_0 4
#define K2_1 5

// ws layout (float offsets)
#define U3S0_OFF 0                          // [23][816]
#define U3S1_OFF (K3_0*NT3)                 // [3][33][816]
#define U2S0_OFF (U3S1_OFF + 3*K3_1*NT3)    // [4][136]
#define U2S1_OFF (U2S0_OFF + K2_0*NT2)      // [3][5][136]
#define LISTS_OFF (U2S1_OFF + 3*K2_1*NT2)   // int[10][2048]
#define CNT_OFF (LISTS_OFF + EN*BN)         // int[10]
#define TALL_OFF (((CNT_OFF + EN) + 3) & ~3)        // float4[1280][968]
#define WS_NEED_BYTES ((size_t)(TALL_OFF + (size_t)EN*CN*NTT*4) * 4)

#define PREP_TOT (K3_0*NT3 + 3*K3_1*NT3 + K2_0*NT2 + 3*K2_1*NT2)  // 102136
#define PREP_BLOCKS ((PREP_TOT + 255) / 256)                       // 400

__global__ __launch_bounds__(256) void prep_sym(
    const float* __restrict__ U3_0, const float* __restrict__ U2_0,
    const float* __restrict__ U3_1, const float* __restrict__ U2_1,
    const float* __restrict__ yg, float* __restrict__ ws)
{
    const int bid = blockIdx.x, tid = threadIdx.x;
    if (bid < PREP_BLOCKS) {
        const int N0 = K3_0*NT3, N1 = 3*K3_1*NT3, P0 = K2_0*NT2;
        const int it = bid*256 + tid;
        if (it >= PREP_TOT) return;
        if (it < N0 + N1) {
            const float* U3; int m, k, K, t, dst;
            if (it < N0) { U3 = U3_0; K = K3_0; m = 0; k = it / NT3; t = it - k*NT3; dst = U3S0_OFF + it; }
            else { int r = it - N0; U3 = U3_1; K = K3_1; int mk = r / NT3; t = r - mk*NT3;
                   m = mk / K3_1; k = mk - m*K3_1; dst = U3S1_OFF + r; }
            // unrank t -> (a<=b<=cc), lexicographic (matches sc_apply loop order)
            int a = 0, rem = t;
            while (rem >= ((16-a)*(17-a))/2) { rem -= ((16-a)*(17-a))/2; ++a; }
            int b = a;
            while (rem >= 16-b) { rem -= 16-b; ++b; }
            const int cc = b + rem;
            #define AT3(i,j,l) U3[(size_t)(((m*16+(i))*16+(j))*16+(l))*K + k]
            float D = AT3(a,b,cc) + AT3(a,cc,b) + AT3(b,a,cc)
                    + AT3(b,cc,a) + AT3(cc,a,b) + AT3(cc,b,a);
            #undef AT3
            const int eq = (a==b) + (b==cc);
            D *= (eq==2) ? (1.f/6.f) : (eq==1) ? 0.5f : 1.f;
            ws[dst] = D;
        } else {
            const int it2 = it - (N0+N1);
            const float* U2; int m, k, K, pr, dst;
            if (it2 < P0) { U2 = U2_0; K = K2_0; m = 0; k = it2 / NT2; pr = it2 - k*NT2; dst = U2S0_OFF + it2; }
            else { int r = it2 - P0; U2 = U2_1; K = K2_1; int mk = r / NT2; pr = r - mk*NT2;
                   m = mk / K2_1; k = mk - m*K2_1; dst = U2S1_OFF + r; }
            int a = 0, rem = pr;
            while (rem >= 16-a) { rem -= 16-a; ++a; }
            const int b = a + rem;
            float D = U2[(size_t)((m*16+a)*16+b)*K + k]
                    + U2[(size_t)((m*16+b)*16+a)*K + k];
            if (a == b) D *= 0.5f;
            ws[dst] = D;
        }
    } else if (bid < PREP_BLOCKS + EN) {
        const int e = bid - PREP_BLOCKS;
        __shared__ int lcnt;
        if (tid == 0) lcnt = 0;
        __syncthreads();
        int* lists = (int*)(ws + LISTS_OFF);
        for (int b = tid; b < BN; b += 256) {
            if (yg[b*EN + e] > 0.5f) {
                int p = atomicAdd(&lcnt, 1);
                lists[e*BN + p] = b;
            }
        }
        __syncthreads();
        if (tid == 0) ((int*)(ws + CNT_OFF))[e] = lcnt;
    }
}

// ---- per-(c,e) fused coefficient tables -> ws[TALL_OFF] -------------------
__global__ __launch_bounds__(256) void sc_build(
    float* __restrict__ ws,
    const float* __restrict__ U1_0, const float* __restrict__ U1_1,
    const float* __restrict__ W3_0, const float* __restrict__ W2_0, const float* __restrict__ W1_0,
    const float* __restrict__ W3_1, const float* __restrict__ W2_1, const float* __restrict__ W1_1)
{
    const int c = blockIdx.x, e = blockIdx.y, tid = threadIdx.x;
    __shared__ float wk30s[K3_0], wk31s[K3_1], wk20s[K2_0], wk21s[K2_1], wk1s[2];
    if (tid < K3_0) wk30s[tid] = W3_0[(e*K3_0 + tid)*CN + c];
    if (tid >= 32 && tid < 32 + K3_1) wk31s[tid-32] = W3_1[(e*K3_1 + (tid-32))*CN + c];
    if (tid >= 72 && tid < 72 + K2_0) wk20s[tid-72] = W2_0[(e*K2_0 + (tid-72))*CN + c];
    if (tid >= 80 && tid < 80 + K2_1) wk21s[tid-80] = W2_1[(e*K2_1 + (tid-80))*CN + c];
    if (tid == 96) wk1s[0] = W1_0[e*CN + c];
    if (tid == 97) wk1s[1] = W1_1[e*CN + c];
    __syncthreads();

    const float* u3s0 = ws + U3S0_OFF;
    const float* u3s1 = ws + U3S1_OFF;
    const float* u2s0 = ws + U2S0_OFF;
    const float* u2s1 = ws + U2S1_OFF;
    float4* out4 = (float4*)(ws + TALL_OFF) + (size_t)(e*CN + c)*NTT;

    for (int g = tid; g < NTT; g += 256) {
        float4 A;
        if (g < NT3) {
            float a0 = 0.f, a1 = 0.f, a2 = 0.f, a3 = 0.f;
#pragma unroll
            for (int k = 0; k < K3_0; ++k)
                a0 = fmaf(u3s0[k*NT3 + g], wk30s[k], a0);
#pragma unroll 8
            for (int k = 0; k < K3_1; ++k) {
                const float w = wk31s[k];
                a1 = fmaf(u3s1[k*NT3 + g], w, a1);
                a2 = fmaf(u3s1[(K3_1 + k)*NT3 + g], w, a2);
                a3 = fmaf(u3s1[(2*K3_1 + k)*NT3 + g], w, a3);
            }
            A = make_float4(a0, a1, a2, a3);
        } else if (g < NT3 + NT2) {
            const int pr = g - NT3;
            float a0 = 0.f, a1 = 0.f, a2 = 0.f, a3 = 0.f;
#pragma unroll
            for (int k = 0; k < K2_0; ++k)
                a0 = fmaf(u2s0[k*NT2 + pr], wk20s[k], a0);
#pragma unroll
            for (int k = 0; k < K2_1; ++k) {
                const float w = wk21s[k];
                a1 = fmaf(u2s1[k*NT2 + pr], w, a1);
                a2 = fmaf(u2s1[(K2_1 + k)*NT2 + pr], w, a2);
                a3 = fmaf(u2s1[(2*K2_1 + k)*NT2 + pr], w, a3);
            }
            A = make_float4(a0, a1, a2, a3);
        } else {
            const int a = g - (NT3 + NT2);
            A = make_float4(U1_0[a]*wk1s[0], U1_1[a]*wk1s[1],
                            U1_1[16+a]*wk1s[1], U1_1[32+a]*wk1s[1]);
        }
        out4[g] = A;
    }
}

// ---- node loop only: low VGPR, high occupancy -----------------------------
__global__ __launch_bounds__(128) void sc_apply(
    const float* __restrict__ xg, const float* __restrict__ ws,
    float* __restrict__ outg)
{
    const int c = blockIdx.x, e = blockIdx.y, tid = threadIdx.x;
    __shared__ float4 Ts[NTT];     // 15488 B fused table
    __shared__ float xs[16*256];   // 16384 B: [i][slot0:0..127 | slot1:128..255]

    const float4* tsrc = (const float4*)(ws + TALL_OFF) + (size_t)(e*CN + c)*NTT;
    for (int i = tid; i < NTT; i += 128) Ts[i] = tsrc[i];

    const int* lists = (const int*)(ws + LISTS_OFF) + e*BN;
    const int cnt = ((const int*)(ws + CNT_OFF))[e];
    __syncthreads();

    for (int base = 0; base < cnt; base += 256) {
        const int s0 = base + tid, s1 = base + tid + 128;
        const bool act0 = s0 < cnt, act1 = s1 < cnt;
        const int n0 = lists[act0 ? s0 : 0];
        const int n1 = lists[act1 ? s1 : 0];
        const float4* p0 = (const float4*)(xg + ((size_t)n0*CN + c)*16);
        const float4* p1 = (const float4*)(xg + ((size_t)n1*CN + c)*16);
#pragma unroll
        for (int d = 0; d < 4; ++d) {
            const float4 v0 = p0[d]; const float4 v1 = p1[d];
            xs[(4*d+0)*256+tid] = v0.x; xs[(4*d+1)*256+tid] = v0.y;
            xs[(4*d+2)*256+tid] = v0.z; xs[(4*d+3)*256+tid] = v0.w;
            xs[(4*d+0)*256+128+tid] = v1.x; xs[(4*d+1)*256+128+tid] = v1.y;
            xs[(4*d+2)*256+128+tid] = v1.z; xs[(4*d+3)*256+128+tid] = v1.w;
        }
        // no barrier needed: each thread touches only its own columns

        float4 acc0 = make_float4(0,0,0,0), acc1 = acc0;
        int t3 = 0, t2 = NT3;
#pragma unroll 1
        for (int a = 0; a < 16; ++a) {
            const float xa0 = xs[a*256+tid];
            const float xa1 = xs[a*256+128+tid];
            float4 tP0 = Ts[NT3+NT2+a], tP1 = tP0;
#pragma unroll 1
            for (int b = a; b < 16; ++b) {
                const float xb0 = xs[b*256+tid];
                const float xb1 = xs[b*256+128+tid];
                const float4 c2v = Ts[t2]; ++t2;
                float4 tB0 = c2v, tB1 = c2v;
#pragma unroll 4
                for (int cc = b; cc < 16; ++cc) {
                    const float xc0 = xs[cc*256+tid];
                    const float xc1 = xs[cc*256+128+tid];
                    const float4 c3v = Ts[t3]; ++t3;
                    tB0.x = fmaf(c3v.x, xc0, tB0.x); tB0.y = fmaf(c3v.y, xc0, tB0.y);
                    tB0.z = fmaf(c3v.z, xc0, tB0.z); tB0.w = fmaf(c3v.w, xc0, tB0.w);
                    tB1.x = fmaf(c3v.x, xc1, tB1.x); tB1.y = fmaf(c3v.y, xc1, tB1.y);
                    tB1.z = fmaf(c3v.z, xc1, tB1.z); tB1.w = fmaf(c3v.w, xc1, tB1.w);
                }
                tP0.x = fmaf(tB0.x, xb0, tP0.x); tP0.y = fmaf(tB0.y, xb0, tP0.y);
                tP0.z = fmaf(tB0.z, xb0, tP0.z); tP0.w = fmaf(tB0.w, xb0, tP0.w);
                tP1.x = fmaf(tB1.x, xb1, tP1.x); tP1.y = fmaf(tB1.y, xb1, tP1.y);
                tP1.z = fmaf(tB1.z, xb1, tP1.z); tP1.w = fmaf(tB1.w, xb1, tP1.w);
            }
            acc0.x = fmaf(tP0.x, xa0, acc0.x); acc0.y = fmaf(tP0.y, xa0, acc0.y);
            acc0.z = fmaf(tP0.z, xa0, acc0.z); acc0.w = fmaf(tP0.w, xa0, acc0.w);
            acc1.x = fmaf(tP1.x, xa1, acc1.x); acc1.y = fmaf(tP1.y, xa1, acc1.y);
            acc1.z = fmaf(tP1.z, xa1, acc1.z); acc1.w = fmaf(tP1.w, xa1, acc1.w);
        }
        if (act0) {
            float* o = outg + (size_t)n0*512;
            o[c] = acc0.x;
            o[128 + c*3 + 0] = acc0.y; o[128 + c*3 + 1] = acc0.z; o[128 + c*3 + 2] = acc0.w;
        }
        if (act1) {
            float* o = outg + (size_t)n1*512;
            o[c] = acc1.x;
            o[128 + c*3 + 0] = acc1.y; o[128 + c*3 + 1] = acc1.z; o[128 + c*3 + 2] = acc1.w;
        }
    }
}

// ---- fallback (round-2 fused kernel, proven): used only if ws is too small
__global__ __launch_bounds__(128) void sc_main_fused(
    const float* __restrict__ xg,
    const float* __restrict__ U1_0, const float* __restrict__ U1_1,
    const float* __restrict__ W3_0, const float* __restrict__ W2_0, const float* __restrict__ W1_0,
    const float* __restrict__ W3_1, const float* __restrict__ W2_1, const float* __restrict__ W1_1,
    const float* __restrict__ ws, float* __restrict__ outg)
{
    const int c = blockIdx.x, e = blockIdx.y, tid = threadIdx.x;
    __shared__ float4 T3s[NT3];
    __shared__ float4 T2s[NT2];
    __shared__ float4 T1s[16];
    __shared__ float xs0[16*128];
    __shared__ float xs1[16*128];
    __shared__ float wk30s[K3_0], wk31s[K3_1], wk20s[K2_0], wk21s[K2_1];

    if (tid < K3_0) wk30s[tid] = W3_0[(e*K3_0 + tid)*CN + c];
    if (tid >= 32 && tid < 32 + K3_1) wk31s[tid-32] = W3_1[(e*K3_1 + (tid-32))*CN + c];
    if (tid >= 72 && tid < 72 + K2_0) wk20s[tid-72] = W2_0[(e*K2_0 + (tid-72))*CN + c];
    if (tid >= 80 && tid < 80 + K2_1) wk21s[tid-80] = W2_1[(e*K2_1 + (tid-80))*CN + c];
    __syncthreads();

    const float* u3s0 = ws + U3S0_OFF;
    const float* u3s1 = ws + U3S1_OFF;
    for (int g = tid; g < NT3/4; g += 128) {
        float4 A0 = make_float4(0,0,0,0), A1 = A0, A2 = A0, A3 = A0;
#pragma unroll
        for (int k = 0; k < K3_0; ++k) {
            const float w = wk30s[k];
            const float4 u = ((const float4*)(u3s0 + k*NT3))[g];
            A0.x = fmaf(u.x, w, A0.x); A0.y = fmaf(u.y, w, A0.y);
            A0.z = fmaf(u.z, w, A0.z); A0.w = fmaf(u.w, w, A0.w);
        }
#pragma unroll 8
        for (int k = 0; k < K3_1; ++k) {
            const float w = wk31s[k];
            const float4 ua = ((const float4*)(u3s1 + k*NT3))[g];
            A1.x = fmaf(ua.x, w, A1.x); A1.y = fmaf(ua.y, w, A1.y);
            A1.z = fmaf(ua.z, w, A1.z); A1.w = fmaf(ua.w, w, A1.w);
            const float4 ub = ((const float4*)(u3s1 + (K3_1 + k)*NT3))[g];
            A2.x = fmaf(ub.x, w, A2.x); A2.y = fmaf(ub.y, w, A2.y);
            A2.z = fmaf(ub.z, w, A2.z); A2.w = fmaf(ub.w, w, A2.w);
            const float4 uc = ((const float4*)(u3s1 + (2*K3_1 + k)*NT3))[g];
            A3.x = fmaf(uc.x, w, A3.x); A3.y = fmaf(uc.y, w, A3.y);
            A3.z = fmaf(uc.z, w, A3.z); A3.w = fmaf(uc.w, w, A3.w);
        }
        T3s[4*g+0] = make_float4(A0.x, A1.x, A2.x, A3.x);
        T3s[4*g+1] = make_float4(A0.y, A1.y, A2.y, A3.y);
        T3s[4*g+2] = make_float4(A0.z, A1.z, A2.z, A3.z);
        T3s[4*g+3] = make_float4(A0.w, A1.w, A2.w, A3.w);
    }
    const float* u2s0 = ws + U2S0_OFF;
    const float* u2s1 = ws + U2S1_OFF;
    for (int g = tid; g < NT2/4; g += 128) {
        float4 A0 = make_float4(0,0,0,0), A1 = A0, A2 = A0, A3 = A0;
#pragma unroll
        for (int k = 0; k < K2_0; ++k) {
            const float w = wk20s[k];
            const float4 u = ((const float4*)(u2s0 + k*NT2))[g];
            A0.x = fmaf(u.x, w, A0.x); A0.y = fmaf(u.y, w, A0.y);
            A0.z = fmaf(u.z, w, A0.z); A0.w = fmaf(u.w, w, A0.w);
        }
#pragma unroll
        for (int k = 0; k < K2_1; ++k) {
            const float w = wk21s[k];
            const float4 ua = ((const float4*)(u2s1 + k*NT2))[g];
            A1.x = fmaf(ua.x, w, A1.x); A1.y = fmaf(ua.y, w, A1.y);
            A1.z = fmaf(ua.z, w, A1.z); A1.w = fmaf(ua.w, w, A1.w);
            const float4 ub = ((const float4*)(u2s1 + (K2_1 + k)*NT2))[g];
            A2.x = fmaf(ub.x, w, A2.x); A2.y = fmaf(ub.y, w, A2.y);
            A2.z = fmaf(ub.z, w, A2.z); A2.w = fmaf(ub.w, w, A2.w);
            const float4 uc = ((const float4*)(u2s1 + (2*K2_1 + k)*NT2))[g];
            A3.x = fmaf(uc.x, w, A3.x); A3.y = fmaf(uc.y, w, A3.y);
            A3.z = fmaf(uc.z, w, A3.z); A3.w = fmaf(uc.w, w, A3.w);
        }
        T2s[4*g+0] = make_float4(A0.x, A1.x, A2.x, A3.x);
        T2s[4*g+1] = make_float4(A0.y, A1.y, A2.y, A3.y);
        T2s[4*g+2] = make_float4(A0.z, A1.z, A2.z, A3.z);
        T2s[4*g+3] = make_float4(A0.w, A1.w, A2.w, A3.w);
    }
    if (tid < 16) {
        const float wk10 = W1_0[e*CN + c];
        const float wk11 = W1_1[e*CN + c];
        const int j = tid;
        T1s[j] = make_float4(U1_0[j]*wk10, U1_1[j]*wk11,
                             U1_1[16+j]*wk11, U1_1[32+j]*wk11);
    }

    const int* lists = (const int*)(ws + LISTS_OFF) + e*BN;
    const int cnt = ((const int*)(ws + CNT_OFF))[e];
    __syncthreads();

    for (int base = 0; base < cnt; base += 256) {
        const int s0 = base + tid, s1 = base + tid + 128;
        const bool act0 = s0 < cnt, act1 = s1 < cnt;
        const int n0 = lists[act0 ? s0 : 0];
        const int n1 = lists[act1 ? s1 : 0];
        const float4* p0 = (const float4*)(xg + ((size_t)n0*CN + c)*16);
        const float4* p1 = (const float4*)(xg + ((size_t)n1*CN + c)*16);
#pragma unroll
        for (int d = 0; d < 4; ++d) {
            const float4 v0 = p0[d]; const float4 v1 = p1[d];
            xs0[(4*d+0)*128+tid] = v0.x; xs0[(4*d+1)*128+tid] = v0.y;
            xs0[(4*d+2)*128+tid] = v0.z; xs0[(4*d+3)*128+tid] = v0.w;
            xs1[(4*d+0)*128+tid] = v1.x; xs1[(4*d+1)*128+tid] = v1.y;
            xs1[(4*d+2)*128+tid] = v1.z; xs1[(4*d+3)*128+tid] = v1.w;
        }
        float4 acc0 = make_float4(0,0,0,0), acc1 = acc0;
        int t3 = 0, t2i = 0;
#pragma unroll 1
        for (int a = 0; a < 16; ++a) {
            const float xa0 = xs0[a*128+tid];
            const float xa1 = xs1[a*128+tid];
            float4 tP0 = T1s[a], tP1 = tP0;
#pragma unroll 1
            for (int b = a; b < 16; ++b) {
                const float xb0 = xs0[b*128+tid];
                const float xb1 = xs1[b*128+tid];
                const float4 c2v = T2s[t2i]; ++t2i;
                float4 tB0 = c2v, tB1 = c2v;
#pragma unroll 4
                for (int cc = b; cc < 16; ++cc) {
                    const float xc0 = xs0[cc*128+tid];
                    const float xc1 = xs1[cc*128+tid];
                    const float4 c3v = T3s[t3]; ++t3;
                    tB0.x = fmaf(c3v.x, xc0, tB0.x); tB0.y = fmaf(c3v.y, xc0, tB0.y);
                    tB0.z = fmaf(c3v.z, xc0, tB0.z); tB0.w = fmaf(c3v.w, xc0, tB0.w);
                    tB1.x = fmaf(c3v.x, xc1, tB1.x); tB1.y = fmaf(c3v.y, xc1, tB1.y);
                    tB1.z = fmaf(c3v.z, xc1, tB1.z); tB1.w = fmaf(c3v.w, xc1, tB1.w);
                }
                tP0.x = fmaf(tB0.x, xb0, tP0.x); tP0.y = fmaf(tB0.y, xb0, tP0.y);
                tP0.z = fmaf(tB0.z, xb0, tP0.z); tP0.w = fmaf(tB0.w, xb0, tP0.w);
                tP1.x = fmaf(tB1.x, xb1, tP1.x); tP1.y = fmaf(tB1.y, xb1, tP1.y);
                tP1.z = fmaf(tB1.z, xb1, tP1.z); tP1.w = fmaf(tB1.w, xb1, tP1.w);
            }
            acc0.x = fmaf(tP0.x, xa0, acc0.x); acc0.y = fmaf(tP0.y, xa0, acc0.y);
            acc0.z = fmaf(tP0.z, xa0, acc0.z); acc0.w = fmaf(tP0.w, xa0, acc0.w);
            acc1.x = fmaf(tP1.x, xa1, acc1.x); acc1.y = fmaf(tP1.y, xa1, acc1.y);
            acc1.z = fmaf(tP1.z, xa1, acc1.z); acc1.w = fmaf(tP1.w, xa1, acc1.w);
        }
        if (act0) {
            float* o = outg + (size_t)n0*512;
            o[c] = acc0.x;
            o[128 + c*3 + 0] = acc0.y; o[128 + c*3 + 1] = acc0.z; o[128 + c*3 + 2] = acc0.w;
        }
        if (act1) {
            float* o = outg + (size_t)n1*512;
            o[c] = acc1.x;
            o[128 + c*3 + 0] = acc1.y; o[128 + c*3 + 1] = acc1.z; o[128 + c*3 + 2] = acc1.w;
        }
    }
}

extern "C" void kernel_launch(void* const* d_in, const int* in_sizes, int n_in,
                              void* d_out, int out_size, void* d_ws, size_t ws_size,
                              hipStream_t stream) {
    const float* x = (const float*)d_in[0];
    const float* y = (const float*)d_in[1];
    const float* U3_0 = (const float*)d_in[2];
    const float* U2_0 = (const float*)d_in[3];
    const float* U1_0 = (const float*)d_in[4];
    const float* W3_0 = (const float*)d_in[5];
    const float* W2_0 = (const float*)d_in[6];
    const float* W1_0 = (const float*)d_in[7];
    const float* U3_1 = (const float*)d_in[8];
    const float* U2_1 = (const float*)d_in[9];
    const float* U1_1 = (const float*)d_in[10];
    const float* W3_1 = (const float*)d_in[11];
    const float* W2_1 = (const float*)d_in[12];
    const float* W1_1 = (const float*)d_in[13];
    float* out = (float*)d_out;
    float* ws = (float*)d_ws;

    prep_sym<<<dim3(PREP_BLOCKS + EN), 256, 0, stream>>>(U3_0, U2_0, U3_1, U2_1, y, ws);
    dim3 grid(CN, EN);
    if (ws_size >= WS_NEED_BYTES) {
        sc_build<<<grid, 256, 0, stream>>>(ws, U1_0, U1_1,
                                           W3_0, W2_0, W1_0, W3_1, W2_1, W1_1);
        sc_apply<<<grid, 128, 0, stream>>>(x, ws, out);
    } else {
        sc_main_fused<<<grid, 128, 0, stream>>>(x, U1_0, U1_1,
                                                W3_0, W2_0, W1_0,
                                                W3_1, W2_1, W1_1, ws, out);
    }
}